// Round 5
// baseline (1021.402 us; speedup 1.0000x reference)
//
#include <hip/hip_runtime.h>
#include <hip/hip_bf16.h>
#include <float.h>

#define NS 32768
#define KER 256
#define TOUT 32513
#define NATOM 256
#define NSTEP 16
#define BATCH 8
#define NBLK 255
#define SW4(i) ((i) + (((i) >> 5) << 2))

__device__ __forceinline__ void cmax(float& ba, float& bs, float& bi,
                                     float oa, float os, float oi) {
    if (oa > ba || (oa == ba && oi < bi)) { ba = oa; bs = os; bi = oi; }
}

__device__ __forceinline__ void fma8(float acc[8], float4 dA, float4 dB,
                                     float4 w0, float4 w1, float4 w2, float4 w3) {
    float w[16] = {w0.x,w0.y,w0.z,w0.w, w1.x,w1.y,w1.z,w1.w,
                   w2.x,w2.y,w2.z,w2.w, w3.x,w3.y,w3.z,w3.w};
    float dv[8] = {dA.x,dA.y,dA.z,dA.w, dB.x,dB.y,dB.z,dB.w};
#pragma unroll
    for (int i = 0; i < 8; ++i)
#pragma unroll
        for (int j = 0; j < 8; ++j)
            acc[j] = fmaf(dv[i], w[i + j], acc[j]);
}

// Full correlation of x with all 256 atoms + per-128-block abs-argmax.
// grid: (16 t-chunks of 2048, 32 atom-groups of 8, 8 batch), block 256.
// Atom-paired, 8 t/thread: acc 16 + window 16 + d 16 regs -> no spill
// (r4's 16-t pairing hit the 256-VGPR ceiling and spilled 144 MB).
__global__ __launch_bounds__(256) void k_init(const float* __restrict__ x,
                                              const float* __restrict__ d,
                                              float4* __restrict__ bm) {
    const int c = blockIdx.x, og = blockIdx.y, b = blockIdx.z;
    const int tid = threadIdx.x;
    __shared__ float rs[2612];   // SW4-swizzled window, idx 0..2319
    __shared__ float dt[2048];   // 8 atoms x 256
    const int base = c * 2048;
    const float* xp = x + (size_t)b * NS;
    for (int i4 = tid; i4 < 580; i4 += 256) {
        const int i = i4 << 2, g = base + i;
        float4 v;
        if (g + 3 < NS) v = *(const float4*)(xp + g);
        else {
            v.x = (g     < NS) ? xp[g]     : 0.f;
            v.y = (g + 1 < NS) ? xp[g + 1] : 0.f;
            v.z = (g + 2 < NS) ? xp[g + 2] : 0.f;
            v.w = (g + 3 < NS) ? xp[g + 3] : 0.f;
        }
        *(float4*)(rs + SW4(i)) = v;
    }
    {
        const float4* ds4 = (const float4*)(d + og * 2048);
        float4* dd4 = (float4*)dt;
        dd4[tid] = ds4[tid];
        dd4[tid + 256] = ds4[tid + 256];
    }
    __syncthreads();
    const int t0 = tid << 3;

#define ARGMAX_STORE(ACC, OGLOB)                                                 \
    do {                                                                         \
        float ba = -1.f, bsg = 0.f, bi = 3.0e7f;                                 \
        _Pragma("unroll")                                                        \
        for (int j = 0; j < 8; ++j) {                                            \
            const int t = base + t0 + j;                                         \
            const float av = fabsf(ACC[j]);                                      \
            if (t < TOUT && av > ba) { ba = av; bsg = ACC[j];                    \
                                       bi = (float)((OGLOB) * TOUT + t); }       \
        }                                                                        \
        _Pragma("unroll")                                                        \
        for (int m = 8; m >= 1; m >>= 1) {                                       \
            float oa = __shfl_xor(ba, m, 16);                                    \
            float os = __shfl_xor(bsg, m, 16);                                   \
            float oi = __shfl_xor(bi, m, 16);                                    \
            cmax(ba, bsg, bi, oa, os, oi);                                       \
        }                                                                        \
        if ((tid & 15) == 0) {                                                   \
            const int blk = (c << 4) + (tid >> 4);                               \
            if (blk < NBLK)                                                      \
                bm[(size_t)(b * NATOM + (OGLOB)) * NBLK + blk] =                 \
                    make_float4(ba, bsg, bi, 0.f);                               \
        }                                                                        \
    } while (0)

    for (int pp = 0; pp < 4; ++pp) {
        const float* dr0 = dt + (pp << 9);
        const float* dr1 = dr0 + 256;
        float acc0[8], acc1[8];
#pragma unroll
        for (int j = 0; j < 8; ++j) { acc0[j] = 0.f; acc1[j] = 0.f; }
        float4 W0 = *(const float4*)(rs + SW4(t0));
        float4 W1 = *(const float4*)(rs + SW4(t0 + 4));
        float4 W2 = *(const float4*)(rs + SW4(t0 + 8));
        float4 W3 = *(const float4*)(rs + SW4(t0 + 12));
#pragma unroll
        for (int kk = 0; kk < 256; kk += 8) {
            float4 d0a = *(const float4*)(dr0 + kk);
            float4 d0b = *(const float4*)(dr0 + kk + 4);
            float4 d1a = *(const float4*)(dr1 + kk);
            float4 d1b = *(const float4*)(dr1 + kk + 4);
            fma8(acc0, d0a, d0b, W0, W1, W2, W3);
            fma8(acc1, d1a, d1b, W0, W1, W2, W3);
            W0 = W2; W1 = W3;
            W2 = *(const float4*)(rs + SW4(t0 + kk + 16));
            W3 = *(const float4*)(rs + SW4(t0 + kk + 20));
        }
        const int oglob0 = (og << 3) + (pp << 1);
        ARGMAX_STORE(acc0, oglob0);
        ARGMAX_STORE(acc1, oglob0 + 1);
    }
#undef ARGMAX_STORE
}

// Per-atom (level-2) maxima over all blocks -> l2 buffer 0.
// grid (32 groups of 8 atoms, 8 b), block 256
__global__ __launch_bounds__(256) void k_lvl2(const float4* __restrict__ bm,
                                              float4* __restrict__ l2) {
    const int b = blockIdx.y;
    const int oglob = blockIdx.x * 8 + (threadIdx.x >> 5);
    const int lane = threadIdx.x & 31;
    const float4* row = bm + (size_t)(b * NATOM + oglob) * NBLK;
    float ba = -1.f, bsg = 0.f, bi = 3.0e7f;
    for (int i = lane; i < NBLK; i += 32) {
        float4 e = row[i];
        cmax(ba, bsg, bi, e.x, e.y, e.z);
    }
#pragma unroll
    for (int m = 16; m >= 1; m >>= 1) {
        float oa = __shfl_xor(ba, m, 32);
        float os = __shfl_xor(bsg, m, 32);
        float oi = __shfl_xor(bi, m, 32);
        cmax(ba, bsg, bi, oa, os, oi);
    }
    if (lane == 0) l2[(b << 8) + oglob] = make_float4(ba, bsg, bi, 0.f);
}

// One MP step: redundant select(step) per block + window update of own 8 atoms.
// l2 is parity double-buffered: read buf[step&1], write buf[(step+1)&1].
// grid (32 atom-groups of 8, 8 b), block 512 (8 waves, wave w -> atom w).
__global__ __launch_bounds__(512) void k_step(const float* __restrict__ x,
                                              const float* __restrict__ d,
                                              float4* __restrict__ bm,
                                              float4* __restrict__ l2,
                                              int* __restrict__ pos_a,
                                              int* __restrict__ atom_a,
                                              float* __restrict__ amp_a,
                                              int step) {
    const int og = blockIdx.x, b = blockIdx.y;
    const int tid = threadIdx.x;
    const int wave = tid >> 6, lane = tid & 63;
    __shared__ float dt[2048];
    __shared__ float rsu[1024];
    __shared__ float4 sred[8];
    __shared__ float4 upd[8][5];
    __shared__ int s_pos[NSTEP], s_atom[NSTEP];
    __shared__ float s_amp[NSTEP];

    ((float4*)dt)[tid] = ((const float4*)(d + og * 2048))[tid];
    if (tid < step) {
        s_pos[tid]  = pos_a[tid * BATCH + b];
        s_atom[tid] = atom_a[tid * BATCH + b];
        s_amp[tid]  = amp_a[tid * BATCH + b];
    }
    const float4* l2r = l2 + (step & 1) * (BATCH * NATOM);
    float4*       l2w = l2 + ((step + 1) & 1) * (BATCH * NATOM);

    // SELECT(step) — identical in every block
    {
        float ba = -1.f, bsg = 0.f, bi = 3.0e7f;
        if (tid < 256) {
            float4 e = l2r[(b << 8) + tid];
            ba = e.x; bsg = e.y; bi = e.z;
        }
#pragma unroll
        for (int m = 32; m >= 1; m >>= 1) {
            float oa = __shfl_xor(ba, m);
            float os = __shfl_xor(bsg, m);
            float oi = __shfl_xor(bi, m);
            cmax(ba, bsg, bi, oa, os, oi);
        }
        if (lane == 0) sred[wave] = make_float4(ba, bsg, bi, 0.f);
    }
    __syncthreads();
    if (tid == 0) {
        float4 r = sred[0];
#pragma unroll
        for (int i = 1; i < 8; ++i) {
            float4 q = sred[i];
            if (q.x > r.x || (q.x == r.x && q.z < r.z)) r = q;
        }
        const int idx = (int)r.z;
        const int atom = idx / TOUT;
        const int pos = idx - atom * TOUT;
        s_pos[step] = pos; s_atom[step] = atom; s_amp[step] = r.y;
        if (og == 0) {
            pos_a[step * BATCH + b] = pos;
            atom_a[step * BATCH + b] = atom;
            amp_a[step * BATCH + b] = r.y;
        }
    }
    __syncthreads();

    // Rebuild residual window from x + full history (reference step order)
    const int p = s_pos[step];
    int tlo = p - 255; if (tlo < 0) tlo = 0;
    int thi = p + 255; if (thi > TOUT - 1) thi = TOUT - 1;
    const int bs0 = tlo >> 7, be0 = thi >> 7;
    const int rbase = bs0 << 7;
    const int nblks = be0 - bs0 + 1;
    const int rlen = (nblks << 7) + 255;
    for (int i = tid; i < rlen; i += 512) {
        const int g = rbase + i;
        float v = (g < NS) ? x[(size_t)b * NS + g] : 0.f;
        for (int s2 = 0; s2 <= step; ++s2) {
            const int off = g - s_pos[s2];
            if (off >= 0 && off < KER)
                v = __fsub_rn(v, __fmul_rn(s_amp[s2], d[s_atom[s2] * KER + off]));
        }
        rsu[SW4(i)] = v;
    }
    __syncthreads();

    // Recompute bm for own 8 atoms over affected blocks (4-way K-split per wave)
    const int lg = lane >> 4, l16 = lane & 15;
    const float* dp = dt + (wave << 8) + (lg << 6);
    const int atomg = (og << 3) + wave;
    for (int bb = 0; bb < nblks; ++bb) {
        const int blk = bs0 + bb;
        const int t0r = (bb << 7) + (l16 << 3) + (lg << 6);
        float acc[8];
#pragma unroll
        for (int j = 0; j < 8; ++j) acc[j] = 0.f;
        float4 A0 = *(const float4*)(rsu + SW4(t0r));
        float4 A1 = *(const float4*)(rsu + SW4(t0r + 4));
        float4 B0 = *(const float4*)(rsu + SW4(t0r + 8));
        float4 B1 = *(const float4*)(rsu + SW4(t0r + 12));
#pragma unroll
        for (int kk = 0; kk < 64; kk += 16) {
            float4 d0 = *(const float4*)(dp + kk);
            float4 d1 = *(const float4*)(dp + kk + 4);
            float4 N0 = *(const float4*)(rsu + SW4(t0r + kk + 16));
            float4 N1 = *(const float4*)(rsu + SW4(t0r + kk + 20));
            fma8(acc, d0, d1, A0, A1, B0, B1);
            float4 d2 = *(const float4*)(dp + kk + 8);
            float4 d3 = *(const float4*)(dp + kk + 12);
            float4 M0 = *(const float4*)(rsu + SW4(t0r + kk + 24));
            float4 M1 = *(const float4*)(rsu + SW4(t0r + kk + 28));
            fma8(acc, d2, d3, B0, B1, N0, N1);
            A0 = N0; A1 = N1; B0 = M0; B1 = M1;
        }
#pragma unroll
        for (int j = 0; j < 8; ++j) {
            acc[j] += __shfl_xor(acc[j], 16);
            acc[j] += __shfl_xor(acc[j], 32);
        }
        float ba = -1.f, bsg = 0.f, bi = 3.0e7f;
        const int tb = rbase + (bb << 7) + (l16 << 3);
#pragma unroll
        for (int j = 0; j < 8; ++j) {
            const int t = tb + j;
            const float av = fabsf(acc[j]);
            if (t < TOUT && av > ba) { ba = av; bsg = acc[j]; bi = (float)(atomg * TOUT + t); }
        }
#pragma unroll
        for (int m = 32; m >= 1; m >>= 1) {
            float oa = __shfl_xor(ba, m);
            float os = __shfl_xor(bsg, m);
            float oi = __shfl_xor(bi, m);
            cmax(ba, bsg, bi, oa, os, oi);
        }
        if (lane == 0) {
            float4 e4 = make_float4(ba, bsg, bi, 0.f);
            bm[(size_t)(b * NATOM + atomg) * NBLK + blk] = e4;
            upd[wave][bb] = e4;
        }
    }
    __syncthreads();

    // l2 refresh (global row, LDS-override for just-updated blocks)
    {
        float ba = -1.f, bsg = 0.f, bi = 3.0e7f;
        const float4* row = bm + (size_t)(b * NATOM + atomg) * NBLK;
        for (int i = lane; i < NBLK; i += 64) {
            float4 e2 = (i >= bs0 && i <= be0) ? upd[wave][i - bs0] : row[i];
            cmax(ba, bsg, bi, e2.x, e2.y, e2.z);
        }
#pragma unroll
        for (int m = 32; m >= 1; m >>= 1) {
            float oa = __shfl_xor(ba, m);
            float os = __shfl_xor(bsg, m);
            float oi = __shfl_xor(bi, m);
            cmax(ba, bsg, bi, oa, os, oi);
        }
        if (lane == 0) l2w[(b << 8) + atomg] = make_float4(ba, bsg, bi, 0.f);
    }
}

// Head; blocks with s==15 compute the final select inline from l2 buf1.
__global__ __launch_bounds__(128) void k_head(const int* __restrict__ pos_a,
                                              const int* __restrict__ atom_a,
                                              const float* __restrict__ amp_a,
                                              const float4* __restrict__ l2,
                                              const float* __restrict__ wpa,
                                              const float* __restrict__ bpa,
                                              const float* __restrict__ wat,
                                              const float* __restrict__ bat,
                                              const float* __restrict__ wr,
                                              const float* __restrict__ br,
                                              float* __restrict__ out) {
    const int s = blockIdx.x, b = blockIdx.y;
    const int o = threadIdx.x;
    __shared__ float4 hred[2];
    __shared__ int sh_pos, sh_atom;
    __shared__ float sh_amp;
    int pos, atom; float amp;
    if (s == NSTEP - 1) {
        const float4* l2r = l2 + ((NSTEP - 1) & 1) * (BATCH * NATOM);
        float ba = -1.f, bsg = 0.f, bi = 3.0e7f;
        float4 e0 = l2r[(b << 8) + o];
        float4 e1 = l2r[(b << 8) + 128 + o];
        cmax(ba, bsg, bi, e0.x, e0.y, e0.z);
        cmax(ba, bsg, bi, e1.x, e1.y, e1.z);
#pragma unroll
        for (int m = 32; m >= 1; m >>= 1) {
            float oa = __shfl_xor(ba, m);
            float os = __shfl_xor(bsg, m);
            float oi = __shfl_xor(bi, m);
            cmax(ba, bsg, bi, oa, os, oi);
        }
        if ((o & 63) == 0) hred[o >> 6] = make_float4(ba, bsg, bi, 0.f);
        __syncthreads();
        if (o == 0) {
            float4 r = hred[0], q = hred[1];
            if (q.x > r.x || (q.x == r.x && q.z < r.z)) r = q;
            const int idx = (int)r.z;
            sh_atom = idx / TOUT;
            sh_pos = idx - sh_atom * TOUT;
            sh_amp = r.y;
        }
        __syncthreads();
        pos = sh_pos; atom = sh_atom; amp = sh_amp;
    } else {
        pos  = pos_a[s * BATCH + b];
        atom = atom_a[s * BATCH + b];
        amp  = amp_a[s * BATCH + b];
    }
    const float posn = (float)pos / 32513.0f;
    float sum = br[o];
    for (int c = 0; c < 128; ++c) {
        float pa = wpa[c * 2] * posn + wpa[c * 2 + 1] * amp + bpa[c];
        float at = wat[c * 256 + atom] + bat[c];
        sum += wr[o * 256 + c] * pa + wr[o * 256 + 128 + c] * at;
    }
    out[(b * 128 + o) * NSTEP + s] = sum;
}

extern "C" void kernel_launch(void* const* d_in, const int* in_sizes, int n_in,
                              void* d_out, int out_size, void* d_ws, size_t ws_size,
                              hipStream_t stream) {
    const float* x   = (const float*)d_in[0];
    const float* d   = (const float*)d_in[1];
    const float* wpa = (const float*)d_in[2];
    const float* bpa = (const float*)d_in[3];
    const float* wat = (const float*)d_in[4];
    const float* bat = (const float*)d_in[5];
    const float* wr  = (const float*)d_in[6];
    const float* br  = (const float*)d_in[7];
    float* out = (float*)d_out;

    char* ws = (char*)d_ws;
    float4* bm = (float4*)ws;                          // 8*256*255*16 = 8,355,840 B
    float4* l2 = (float4*)(ws + 8355840);              // 2*2048*16 = 65,536 B
    int*   pos_a  = (int*)(ws + 8355840 + 65536);
    int*   atom_a = pos_a + NSTEP * BATCH;
    float* amp_a  = (float*)(atom_a + NSTEP * BATCH);

    k_init<<<dim3(16, 32, 8), 256, 0, stream>>>(x, d, bm);
    k_lvl2<<<dim3(32, 8), 256, 0, stream>>>(bm, l2);
    for (int st = 0; st < NSTEP - 1; ++st)
        k_step<<<dim3(32, 8), 512, 0, stream>>>(x, d, bm, l2, pos_a, atom_a, amp_a, st);
    k_head<<<dim3(16, 8), 128, 0, stream>>>(pos_a, atom_a, amp_a, l2,
                                            wpa, bpa, wat, bat, wr, br, out);
}

// Round 6
// 433.588 us; speedup vs baseline: 2.3557x; 2.3557x over previous
//
#include <hip/hip_runtime.h>
#include <hip/hip_bf16.h>
#include <float.h>

#define NS 32768
#define KER 256
#define TOUT 32513
#define NATOM 256
#define NSTEP 16
#define BATCH 8
#define NBLK 255
#define XSTR 33024   // NS + 256 pad (zero-filled)
#define SW4(i) ((i) + (((i) >> 5) << 2))

typedef __attribute__((ext_vector_type(8))) _Float16 half8;
typedef __attribute__((ext_vector_type(4))) float f32x4;
typedef __attribute__((ext_vector_type(4))) unsigned int uint4v;

__device__ __forceinline__ void cmax(float& ba, float& bs, float& bi,
                                     float oa, float os, float oi) {
    if (oa > ba || (oa == ba && oi < bi)) { ba = oa; bs = os; bi = oi; }
}

__device__ __forceinline__ void fma8(float acc[8], float4 dA, float4 dB,
                                     float4 w0, float4 w1, float4 w2, float4 w3) {
    float w[16] = {w0.x,w0.y,w0.z,w0.w, w1.x,w1.y,w1.z,w1.w,
                   w2.x,w2.y,w2.z,w2.w, w3.x,w3.y,w3.z,w3.w};
    float dv[8] = {dA.x,dA.y,dA.z,dA.w, dB.x,dB.y,dB.z,dB.w};
#pragma unroll
    for (int i = 0; i < 8; ++i)
#pragma unroll
        for (int j = 0; j < 8; ++j)
            acc[j] = fmaf(dv[i], w[i + j], acc[j]);
}

// Split x and d into f16 hi/lo. xp[b][i] = (bits(lo)<<16)|bits(hi), zero-padded
// past NS. dh/dl are separate f16 arrays for 16B-aligned A-fragment loads.
__global__ __launch_bounds__(256) void k_prep(const float* __restrict__ x,
                                              const float* __restrict__ d,
                                              unsigned int* __restrict__ xp,
                                              unsigned short* __restrict__ dh,
                                              unsigned short* __restrict__ dl) {
    const int gid = blockIdx.x * 256 + threadIdx.x;
    const int NX = BATCH * XSTR;
    if (gid < NX) {
        const int b = gid / XSTR, i = gid - b * XSTR;
        const float v = (i < NS) ? x[b * NS + i] : 0.f;
        const _Float16 h = (_Float16)v;
        const _Float16 lo = (_Float16)(v - (float)h);
        xp[gid] = ((unsigned int)__builtin_bit_cast(unsigned short, lo) << 16)
                | (unsigned int)__builtin_bit_cast(unsigned short, h);
    } else {
        const int j = gid - NX;
        if (j < NATOM * KER) {
            const float v = d[j];
            const _Float16 h = (_Float16)v;
            const _Float16 lo = (_Float16)(v - (float)h);
            dh[j] = __builtin_bit_cast(unsigned short, h);
            dl[j] = __builtin_bit_cast(unsigned short, lo);
        }
    }
}

// MFMA full correlation + per-128-block abs-argmax.
// grid (128 t-chunks of 256, 16 atom-groups of 16, 8 b), block 256 (4 waves).
// Per wave: 16 atoms x 64 t; 4 n-tiles; K=256 in 8 steps of 32; split-f16:
// acc += Ah*Bl + Al*Bh + Ah*Bh  (3 MFMAs, ~f32 precision).
__global__ __launch_bounds__(256) void k_init(const unsigned int* __restrict__ xp,
                                              const unsigned short* __restrict__ dh,
                                              const unsigned short* __restrict__ dl,
                                              float4* __restrict__ bm) {
    const int c = blockIdx.x, mg = blockIdx.y, b = blockIdx.z;
    const int tid = threadIdx.x;
    const int w = tid >> 6, l = tid & 63;
    const int l15 = l & 15, g = l >> 4;
    __shared__ unsigned int xw[512];
    __shared__ float4 wmax[4][16];
    const int t0 = c << 8;
    xw[tid] = xp[b * XSTR + t0 + tid];
    xw[tid + 256] = xp[b * XSTR + t0 + 256 + tid];
    __syncthreads();

    f32x4 acc0 = {0.f,0.f,0.f,0.f}, acc1 = {0.f,0.f,0.f,0.f};
    f32x4 acc2 = {0.f,0.f,0.f,0.f}, acc3 = {0.f,0.f,0.f,0.f};
    const int arow = (mg << 4) + l15;
    const unsigned short* dhp = dh + arow * 256 + (g << 3);
    const unsigned short* dlp = dl + arow * 256 + (g << 3);

#pragma unroll 2
    for (int kk = 0; kk < 8; ++kk) {
        const half8 ah = *(const half8*)(dhp + (kk << 5));
        const half8 al = *(const half8*)(dlp + (kk << 5));
        const int sbase = (w << 6) + (kk << 5) + l15 + (g << 3);
#pragma unroll
        for (int nt = 0; nt < 4; ++nt) {
            const int s = sbase + (nt << 4);
            const unsigned int w0 = xw[s],     w1 = xw[s + 1];
            const unsigned int w2 = xw[s + 2], w3 = xw[s + 3];
            const unsigned int w4 = xw[s + 4], w5 = xw[s + 5];
            const unsigned int w6 = xw[s + 6], w7 = xw[s + 7];
            uint4v hv = { (w0 & 0xffffu) | (w1 << 16),
                          (w2 & 0xffffu) | (w3 << 16),
                          (w4 & 0xffffu) | (w5 << 16),
                          (w6 & 0xffffu) | (w7 << 16) };
            uint4v lv = { (w0 >> 16) | (w1 & 0xffff0000u),
                          (w2 >> 16) | (w3 & 0xffff0000u),
                          (w4 >> 16) | (w5 & 0xffff0000u),
                          (w6 >> 16) | (w7 & 0xffff0000u) };
            const half8 bh = __builtin_bit_cast(half8, hv);
            const half8 bl = __builtin_bit_cast(half8, lv);
            f32x4 a = (nt == 0) ? acc0 : (nt == 1) ? acc1 : (nt == 2) ? acc2 : acc3;
            a = __builtin_amdgcn_mfma_f32_16x16x32_f16(ah, bl, a, 0, 0, 0);
            a = __builtin_amdgcn_mfma_f32_16x16x32_f16(al, bh, a, 0, 0, 0);
            a = __builtin_amdgcn_mfma_f32_16x16x32_f16(ah, bh, a, 0, 0, 0);
            if (nt == 0) acc0 = a; else if (nt == 1) acc1 = a;
            else if (nt == 2) acc2 = a; else acc3 = a;
        }
    }

    // epilogue: per-row (atom = mg*16 + 4*g + r) argmax over this wave's 64 t
#pragma unroll
    for (int r = 0; r < 4; ++r) {
        float ba = -1.f, bsg = 0.f, bi = 3.0e7f;
        const int atomg = (mg << 4) + (g << 2) + r;
#pragma unroll
        for (int nt = 0; nt < 4; ++nt) {
            const int t = t0 + (w << 6) + (nt << 4) + l15;
            const float v = (nt == 0) ? acc0[r] : (nt == 1) ? acc1[r]
                          : (nt == 2) ? acc2[r] : acc3[r];
            const float av = fabsf(v);
            if (t < TOUT && av > ba) { ba = av; bsg = v; bi = (float)(atomg * TOUT + t); }
        }
#pragma unroll
        for (int m = 1; m <= 8; m <<= 1) {
            float oa = __shfl_xor(ba, m, 16);
            float os = __shfl_xor(bsg, m, 16);
            float oi = __shfl_xor(bi, m, 16);
            cmax(ba, bsg, bi, oa, os, oi);
        }
        if (l15 == 0) wmax[w][(g << 2) + r] = make_float4(ba, bsg, bi, 0.f);
    }
    __syncthreads();
    if (tid < 32) {
        const int a = tid & 15, p = tid >> 4;
        float4 e1 = wmax[2 * p][a];
        const float4 e2 = wmax[2 * p + 1][a];
        float ba = e1.x, bsg = e1.y, bi = e1.z;
        cmax(ba, bsg, bi, e2.x, e2.y, e2.z);
        const int blk = (c << 1) + p;
        if (blk < NBLK)
            bm[(size_t)((b << 8) + (mg << 4) + a) * NBLK + blk] =
                make_float4(ba, bsg, bi, 0.f);
    }
}

// Per-atom (level-2) maxima over all blocks -> l2 buffer 0.
__global__ __launch_bounds__(256) void k_lvl2(const float4* __restrict__ bm,
                                              float4* __restrict__ l2) {
    const int b = blockIdx.y;
    const int oglob = blockIdx.x * 8 + (threadIdx.x >> 5);
    const int lane = threadIdx.x & 31;
    const float4* row = bm + (size_t)(b * NATOM + oglob) * NBLK;
    float ba = -1.f, bsg = 0.f, bi = 3.0e7f;
    for (int i = lane; i < NBLK; i += 32) {
        float4 e = row[i];
        cmax(ba, bsg, bi, e.x, e.y, e.z);
    }
#pragma unroll
    for (int m = 16; m >= 1; m >>= 1) {
        float oa = __shfl_xor(ba, m, 32);
        float os = __shfl_xor(bsg, m, 32);
        float oi = __shfl_xor(bi, m, 32);
        cmax(ba, bsg, bi, oa, os, oi);
    }
    if (lane == 0) l2[(b << 8) + oglob] = make_float4(ba, bsg, bi, 0.f);
}

// One MP step (unchanged from r3/r4/r5 passing versions).
__global__ __launch_bounds__(512) void k_step(const float* __restrict__ x,
                                              const float* __restrict__ d,
                                              float4* __restrict__ bm,
                                              float4* __restrict__ l2,
                                              int* __restrict__ pos_a,
                                              int* __restrict__ atom_a,
                                              float* __restrict__ amp_a,
                                              int step) {
    const int og = blockIdx.x, b = blockIdx.y;
    const int tid = threadIdx.x;
    const int wave = tid >> 6, lane = tid & 63;
    __shared__ float dt[2048];
    __shared__ float rsu[1024];
    __shared__ float4 sred[8];
    __shared__ float4 upd[8][5];
    __shared__ int s_pos[NSTEP], s_atom[NSTEP];
    __shared__ float s_amp[NSTEP];

    ((float4*)dt)[tid] = ((const float4*)(d + og * 2048))[tid];
    if (tid < step) {
        s_pos[tid]  = pos_a[tid * BATCH + b];
        s_atom[tid] = atom_a[tid * BATCH + b];
        s_amp[tid]  = amp_a[tid * BATCH + b];
    }
    const float4* l2r = l2 + (step & 1) * (BATCH * NATOM);
    float4*       l2w = l2 + ((step + 1) & 1) * (BATCH * NATOM);

    {
        float ba = -1.f, bsg = 0.f, bi = 3.0e7f;
        if (tid < 256) {
            float4 e = l2r[(b << 8) + tid];
            ba = e.x; bsg = e.y; bi = e.z;
        }
#pragma unroll
        for (int m = 32; m >= 1; m >>= 1) {
            float oa = __shfl_xor(ba, m);
            float os = __shfl_xor(bsg, m);
            float oi = __shfl_xor(bi, m);
            cmax(ba, bsg, bi, oa, os, oi);
        }
        if (lane == 0) sred[wave] = make_float4(ba, bsg, bi, 0.f);
    }
    __syncthreads();
    if (tid == 0) {
        float4 r = sred[0];
#pragma unroll
        for (int i = 1; i < 8; ++i) {
            float4 q = sred[i];
            if (q.x > r.x || (q.x == r.x && q.z < r.z)) r = q;
        }
        const int idx = (int)r.z;
        const int atom = idx / TOUT;
        const int pos = idx - atom * TOUT;
        s_pos[step] = pos; s_atom[step] = atom; s_amp[step] = r.y;
        if (og == 0) {
            pos_a[step * BATCH + b] = pos;
            atom_a[step * BATCH + b] = atom;
            amp_a[step * BATCH + b] = r.y;
        }
    }
    __syncthreads();

    const int p = s_pos[step];
    int tlo = p - 255; if (tlo < 0) tlo = 0;
    int thi = p + 255; if (thi > TOUT - 1) thi = TOUT - 1;
    const int bs0 = tlo >> 7, be0 = thi >> 7;
    const int rbase = bs0 << 7;
    const int nblks = be0 - bs0 + 1;
    const int rlen = (nblks << 7) + 255;
    for (int i = tid; i < rlen; i += 512) {
        const int g = rbase + i;
        float v = (g < NS) ? x[(size_t)b * NS + g] : 0.f;
        for (int s2 = 0; s2 <= step; ++s2) {
            const int off = g - s_pos[s2];
            if (off >= 0 && off < KER)
                v = __fsub_rn(v, __fmul_rn(s_amp[s2], d[s_atom[s2] * KER + off]));
        }
        rsu[SW4(i)] = v;
    }
    __syncthreads();

    const int lg = lane >> 4, l16 = lane & 15;
    const float* dp = dt + (wave << 8) + (lg << 6);
    const int atomg = (og << 3) + wave;
    for (int bb = 0; bb < nblks; ++bb) {
        const int blk = bs0 + bb;
        const int t0r = (bb << 7) + (l16 << 3) + (lg << 6);
        float acc[8];
#pragma unroll
        for (int j = 0; j < 8; ++j) acc[j] = 0.f;
        float4 A0 = *(const float4*)(rsu + SW4(t0r));
        float4 A1 = *(const float4*)(rsu + SW4(t0r + 4));
        float4 B0 = *(const float4*)(rsu + SW4(t0r + 8));
        float4 B1 = *(const float4*)(rsu + SW4(t0r + 12));
#pragma unroll
        for (int kk = 0; kk < 64; kk += 16) {
            float4 d0 = *(const float4*)(dp + kk);
            float4 d1 = *(const float4*)(dp + kk + 4);
            float4 N0 = *(const float4*)(rsu + SW4(t0r + kk + 16));
            float4 N1 = *(const float4*)(rsu + SW4(t0r + kk + 20));
            fma8(acc, d0, d1, A0, A1, B0, B1);
            float4 d2 = *(const float4*)(dp + kk + 8);
            float4 d3 = *(const float4*)(dp + kk + 12);
            float4 M0 = *(const float4*)(rsu + SW4(t0r + kk + 24));
            float4 M1 = *(const float4*)(rsu + SW4(t0r + kk + 28));
            fma8(acc, d2, d3, B0, B1, N0, N1);
            A0 = N0; A1 = N1; B0 = M0; B1 = M1;
        }
#pragma unroll
        for (int j = 0; j < 8; ++j) {
            acc[j] += __shfl_xor(acc[j], 16);
            acc[j] += __shfl_xor(acc[j], 32);
        }
        float ba = -1.f, bsg = 0.f, bi = 3.0e7f;
        const int tb = rbase + (bb << 7) + (l16 << 3);
#pragma unroll
        for (int j = 0; j < 8; ++j) {
            const int t = tb + j;
            const float av = fabsf(acc[j]);
            if (t < TOUT && av > ba) { ba = av; bsg = acc[j]; bi = (float)(atomg * TOUT + t); }
        }
#pragma unroll
        for (int m = 32; m >= 1; m >>= 1) {
            float oa = __shfl_xor(ba, m);
            float os = __shfl_xor(bsg, m);
            float oi = __shfl_xor(bi, m);
            cmax(ba, bsg, bi, oa, os, oi);
        }
        if (lane == 0) {
            float4 e4 = make_float4(ba, bsg, bi, 0.f);
            bm[(size_t)(b * NATOM + atomg) * NBLK + blk] = e4;
            upd[wave][bb] = e4;
        }
    }
    __syncthreads();

    {
        float ba = -1.f, bsg = 0.f, bi = 3.0e7f;
        const float4* row = bm + (size_t)(b * NATOM + atomg) * NBLK;
        for (int i = lane; i < NBLK; i += 64) {
            float4 e2 = (i >= bs0 && i <= be0) ? upd[wave][i - bs0] : row[i];
            cmax(ba, bsg, bi, e2.x, e2.y, e2.z);
        }
#pragma unroll
        for (int m = 32; m >= 1; m >>= 1) {
            float oa = __shfl_xor(ba, m);
            float os = __shfl_xor(bsg, m);
            float oi = __shfl_xor(bi, m);
            cmax(ba, bsg, bi, oa, os, oi);
        }
        if (lane == 0) l2w[(b << 8) + atomg] = make_float4(ba, bsg, bi, 0.f);
    }
}

// Head; blocks with s==15 compute the final select inline from l2 buf1.
__global__ __launch_bounds__(128) void k_head(const int* __restrict__ pos_a,
                                              const int* __restrict__ atom_a,
                                              const float* __restrict__ amp_a,
                                              const float4* __restrict__ l2,
                                              const float* __restrict__ wpa,
                                              const float* __restrict__ bpa,
                                              const float* __restrict__ wat,
                                              const float* __restrict__ bat,
                                              const float* __restrict__ wr,
                                              const float* __restrict__ br,
                                              float* __restrict__ out) {
    const int s = blockIdx.x, b = blockIdx.y;
    const int o = threadIdx.x;
    __shared__ float4 hred[2];
    __shared__ int sh_pos, sh_atom;
    __shared__ float sh_amp;
    int pos, atom; float amp;
    if (s == NSTEP - 1) {
        const float4* l2r = l2 + ((NSTEP - 1) & 1) * (BATCH * NATOM);
        float ba = -1.f, bsg = 0.f, bi = 3.0e7f;
        float4 e0 = l2r[(b << 8) + o];
        float4 e1 = l2r[(b << 8) + 128 + o];
        cmax(ba, bsg, bi, e0.x, e0.y, e0.z);
        cmax(ba, bsg, bi, e1.x, e1.y, e1.z);
#pragma unroll
        for (int m = 32; m >= 1; m >>= 1) {
            float oa = __shfl_xor(ba, m);
            float os = __shfl_xor(bsg, m);
            float oi = __shfl_xor(bi, m);
            cmax(ba, bsg, bi, oa, os, oi);
        }
        if ((o & 63) == 0) hred[o >> 6] = make_float4(ba, bsg, bi, 0.f);
        __syncthreads();
        if (o == 0) {
            float4 r = hred[0], q = hred[1];
            if (q.x > r.x || (q.x == r.x && q.z < r.z)) r = q;
            const int idx = (int)r.z;
            sh_atom = idx / TOUT;
            sh_pos = idx - sh_atom * TOUT;
            sh_amp = r.y;
        }
        __syncthreads();
        pos = sh_pos; atom = sh_atom; amp = sh_amp;
    } else {
        pos  = pos_a[s * BATCH + b];
        atom = atom_a[s * BATCH + b];
        amp  = amp_a[s * BATCH + b];
    }
    const float posn = (float)pos / 32513.0f;
    float sum = br[o];
    for (int c = 0; c < 128; ++c) {
        float pa = wpa[c * 2] * posn + wpa[c * 2 + 1] * amp + bpa[c];
        float at = wat[c * 256 + atom] + bat[c];
        sum += wr[o * 256 + c] * pa + wr[o * 256 + 128 + c] * at;
    }
    out[(b * 128 + o) * NSTEP + s] = sum;
}

extern "C" void kernel_launch(void* const* d_in, const int* in_sizes, int n_in,
                              void* d_out, int out_size, void* d_ws, size_t ws_size,
                              hipStream_t stream) {
    const float* x   = (const float*)d_in[0];
    const float* d   = (const float*)d_in[1];
    const float* wpa = (const float*)d_in[2];
    const float* bpa = (const float*)d_in[3];
    const float* wat = (const float*)d_in[4];
    const float* bat = (const float*)d_in[5];
    const float* wr  = (const float*)d_in[6];
    const float* br  = (const float*)d_in[7];
    float* out = (float*)d_out;

    char* ws = (char*)d_ws;
    float4* bm = (float4*)ws;                              // 8,355,840 B
    float4* l2 = (float4*)(ws + 8355840);                  // 65,536 B
    int*   pos_a  = (int*)(ws + 8355840 + 65536);
    int*   atom_a = pos_a + NSTEP * BATCH;
    float* amp_a  = (float*)(atom_a + NSTEP * BATCH);
    unsigned int*   xp = (unsigned int*)(ws + 8355840 + 65536 + 512);      // 1,056,768 B
    unsigned short* dh = (unsigned short*)(ws + 8355840 + 65536 + 512 + 1056768);  // 131,072 B
    unsigned short* dl = dh + NATOM * KER;                                 // 131,072 B

    const int prep_n = BATCH * XSTR + NATOM * KER;
    k_prep<<<(prep_n + 255) / 256, 256, 0, stream>>>(x, d, xp, dh, dl);
    k_init<<<dim3(128, 16, 8), 256, 0, stream>>>(xp, dh, dl, bm);
    k_lvl2<<<dim3(32, 8), 256, 0, stream>>>(bm, l2);
    for (int st = 0; st < NSTEP - 1; ++st)
        k_step<<<dim3(32, 8), 512, 0, stream>>>(x, d, bm, l2, pos_a, atom_a, amp_a, st);
    k_head<<<dim3(16, 8), 128, 0, stream>>>(pos_a, atom_a, amp_a, l2,
                                            wpa, bpa, wat, bat, wr, br, out);
}